// Round 1
// baseline (5710.138 us; speedup 1.0000x reference)
//
#include <hip/hip_runtime.h>
#include <hip/hip_bf16.h>
#include <stdint.h>

#define T_STEPS 512
#define BATCH   256
#define INDIM   512
#define HID     256

using short8 = __attribute__((ext_vector_type(8))) short;
using f32x4  = __attribute__((ext_vector_type(4))) float;

__device__ inline unsigned short f2bf(float f) {
  unsigned u = __float_as_uint(f);
  unsigned r = (u + 0x7fffu + ((u >> 16) & 1u)) >> 16;
  return (unsigned short)r;
}
__device__ inline float bflo(unsigned u) { return __uint_as_float(u << 16); }
__device__ inline float bfhi(unsigned u) { return __uint_as_float(u & 0xffff0000u); }
__device__ inline float sigm(float x)   { return __builtin_amdgcn_rcpf(1.0f + __expf(-x)); }
__device__ inline float tanh_f(float x) { return 2.0f * __builtin_amdgcn_rcpf(1.0f + __expf(-2.0f * x)) - 1.0f; }

// ---------------- prep: pack weights ----------------
// WxC   : [1024 cols][512 k]  bf16 (col-major slice of Wx for MFMA B staging)
// WhT2  : [4 gates][128 k2][256 cols] u32 = packed (bf16 k=2*k2, bf16 k=2*k2+1)
// cvec  : [1024] = bias + theta
__global__ __launch_bounds__(256) void prep_kernel(
    const float* __restrict__ Wf, const float* __restrict__ Wi,
    const float* __restrict__ Wg, const float* __restrict__ Wo,
    const float* __restrict__ bf_, const float* __restrict__ bi_,
    const float* __restrict__ bg_, const float* __restrict__ bo_,
    const float* __restrict__ thf, const float* __restrict__ thi,
    const float* __restrict__ thg, const float* __restrict__ tho,
    unsigned short* __restrict__ WxC, unsigned* __restrict__ WhT2,
    float* __restrict__ cvec)
{
  int j = blockIdx.x;            // 0..1023
  int g = j >> 8, col = j & 255;
  const float* W  = (g==0)?Wf:(g==1)?Wi:(g==2)?Wg:Wo;
  const float* bb = (g==0)?bf_:(g==1)?bi_:(g==2)?bg_:bo_;
  const float* th = (g==0)?thf:(g==1)?thi:(g==2)?thg:tho;
  const float* wrow = W + (size_t)col * 768;
  for (int k = threadIdx.x; k < 512; k += blockDim.x)
    WxC[(size_t)j * 512 + k] = f2bf(wrow[k]);
  for (int k2 = threadIdx.x; k2 < 128; k2 += blockDim.x) {
    unsigned lo = f2bf(wrow[512 + 2*k2]);
    unsigned hi = f2bf(wrow[512 + 2*k2 + 1]);
    WhT2[(size_t)(g*128 + k2)*256 + col] = lo | (hi << 16);
  }
  if (threadIdx.x == 0) cvec[j] = bb[col] + th[col];
}

// ---------------- xgemm: Zx = bf16(X) @ WxC^T + cvec ----------------
// X  : [M][512] fp32 row-major (M = CT*256), Zx : [M][1024] fp32
__global__ __launch_bounds__(256) void xgemm_kernel(
    const float* __restrict__ X, const unsigned short* __restrict__ WxC,
    const float* __restrict__ cvec, float* __restrict__ Zx)
{
  __shared__ unsigned short a_sm[128][40];   // +8 pad: 80B stride, 2-way max
  __shared__ unsigned short b_sm[128][40];
  int tid = threadIdx.x;
  int rowbase = blockIdx.y * 128;
  int colbase = blockIdx.x * 128;
  int wave = tid >> 6, lane = tid & 63;
  int wr = wave >> 1, wc = wave & 1;
  int l15 = lane & 15, kg = (lane >> 4) * 8;

  f32x4 acc[4][4];
#pragma unroll
  for (int i = 0; i < 4; i++)
#pragma unroll
    for (int j = 0; j < 4; j++) acc[i][j] = (f32x4)0.0f;

  int r  = tid >> 1;
  int kh = (tid & 1) * 16;

  for (int kb = 0; kb < 512; kb += 32) {
    // stage A (fp32 -> bf16), rows of X
    const float* ap = X + (size_t)(rowbase + r) * 512 + kb + kh;
    unsigned short tmp[16];
#pragma unroll
    for (int i = 0; i < 16; i++) tmp[i] = f2bf(ap[i]);
    *(short8*)&a_sm[r][kh]     = *(short8*)&tmp[0];
    *(short8*)&a_sm[r][kh + 8] = *(short8*)&tmp[8];
    // stage B (bf16 direct), col-major Wx
    const unsigned short* bp = WxC + (size_t)(colbase + r) * 512 + kb + kh;
    *(short8*)&b_sm[r][kh]     = *(const short8*)bp;
    *(short8*)&b_sm[r][kh + 8] = *(const short8*)(bp + 8);
    __syncthreads();

    short8 af[4], bfr[4];
#pragma unroll
    for (int mi = 0; mi < 4; mi++) af[mi]  = *(const short8*)&a_sm[wr*64 + mi*16 + l15][kg];
#pragma unroll
    for (int ni = 0; ni < 4; ni++) bfr[ni] = *(const short8*)&b_sm[wc*64 + ni*16 + l15][kg];
#pragma unroll
    for (int mi = 0; mi < 4; mi++)
#pragma unroll
      for (int ni = 0; ni < 4; ni++)
        acc[mi][ni] = __builtin_amdgcn_mfma_f32_16x16x32_bf16(af[mi], bfr[ni], acc[mi][ni], 0, 0, 0);
    __syncthreads();
  }

  int lg = lane >> 4;
#pragma unroll
  for (int mi = 0; mi < 4; mi++) {
#pragma unroll
    for (int ni = 0; ni < 4; ni++) {
      int c = colbase + wc*64 + ni*16 + l15;
      float cv = cvec[c];
#pragma unroll
      for (int reg = 0; reg < 4; reg++) {
        int row = rowbase + wr*64 + mi*16 + lg*4 + reg;
        Zx[(size_t)row * 1024 + c] = acc[mi][ni][reg] + cv;
      }
    }
  }
}

// ---------------- step kernel ----------------
// grid: 256 WGs = 64 batch-groups (4 rows each) x 4 gates; 512 threads.
// Does: [t>0] LSTM update for step t-1 (redundant per gate-WG; gate0 writes
// cx + stacked output), then z(t) = hx @ WhT + Zx(t), cumprod scan, activation.
__global__ __launch_bounds__(512) void step_kernel(
    int t, int t_local,
    const float* __restrict__ Zx,        // chunk base [CT*256][1024]
    const unsigned* __restrict__ WhT2,   // [4][128][256]
    float* __restrict__ gates0, float* __restrict__ gates1,  // [4][256][256]
    float* __restrict__ cx0, float* __restrict__ cx1,        // [256][256]
    float* __restrict__ out)
{
  __shared__ float hx_lds[4][256];
  __shared__ float zred[2][4][256];
  int bid = blockIdx.x;
  int bg = bid >> 2, g = bid & 3;
  int tid = threadIdx.x;

  const float* grd = (t & 1) ? gates0 : gates1;   // gates(t-1) at buf[(t-1)&1]
  float*       gwr = (t & 1) ? gates1 : gates0;   // gates(t)   at buf[t&1]
  const float* crd = (t & 1) ? cx1 : cx0;         // cx(t-2)    at buf[t&1]
  float*       cwr = (t & 1) ? cx0 : cx1;         // cx(t-1)    at buf[(t-1)&1]

  // ---- phase 0: update for t-1 ----
  if (t > 0) {
#pragma unroll
    for (int p = 0; p < 2; p++) {
      int e = tid + p * 512;
      int bi = e >> 8, col = e & 255;
      int b = bg * 4 + bi;
      float fv = grd[(size_t)(0*256 + b)*256 + col];
      float iv = grd[(size_t)(1*256 + b)*256 + col];
      float gv = grd[(size_t)(2*256 + b)*256 + col];
      float ov = grd[(size_t)(3*256 + b)*256 + col];
      float cold = (t >= 2) ? crd[(size_t)b*256 + col] : 0.0f;
      float cnew = fv * cold + iv * gv;
      float h = ov * tanh_f(cnew);
      hx_lds[bi][col] = h;
      if (g == 0) {
        cwr[(size_t)b*256 + col] = cnew;
        out[(size_t)(t-1)*BATCH*HID + (size_t)b*256 + col] = h;
        if (t == T_STEPS) {
          out[(size_t)T_STEPS*BATCH*HID + (size_t)b*256 + col] = h;
          out[(size_t)T_STEPS*BATCH*HID + BATCH*HID + (size_t)b*256 + col] = cnew;
        }
      }
    }
  }
  __syncthreads();
  if (t == T_STEPS) return;

  // ---- phase 1: z = hx @ WhT (split K across 2 halves) ----
  int col = tid & 255, khalf = tid >> 8;
  float acc0 = 0.f, acc1 = 0.f, acc2 = 0.f, acc3 = 0.f;
  if (t > 0) {
    const unsigned* wp = WhT2 + (size_t)(g*128 + khalf*64)*256 + col;
    int kofs0 = khalf * 128;
#pragma unroll 4
    for (int k4 = 0; k4 < 32; k4++) {          // 4 k per iter
      unsigned u0 = wp[(size_t)(2*k4    )*256];
      unsigned u1 = wp[(size_t)(2*k4 + 1)*256];
      float w0 = bflo(u0), w1 = bfhi(u0), w2 = bflo(u1), w3 = bfhi(u1);
      int kofs = kofs0 + 4*k4;
      f32x4 h0 = *(const f32x4*)&hx_lds[0][kofs];
      f32x4 h1 = *(const f32x4*)&hx_lds[1][kofs];
      f32x4 h2 = *(const f32x4*)&hx_lds[2][kofs];
      f32x4 h3 = *(const f32x4*)&hx_lds[3][kofs];
      acc0 += h0[0]*w0 + h0[1]*w1 + h0[2]*w2 + h0[3]*w3;
      acc1 += h1[0]*w0 + h1[1]*w1 + h1[2]*w2 + h1[3]*w3;
      acc2 += h2[0]*w0 + h2[1]*w1 + h2[2]*w2 + h2[3]*w3;
      acc3 += h3[0]*w0 + h3[1]*w1 + h3[2]*w2 + h3[3]*w3;
    }
  }
  zred[khalf][0][col] = acc0;
  zred[khalf][1][col] = acc1;
  zred[khalf][2][col] = acc2;
  zred[khalf][3][col] = acc3;
  __syncthreads();

  // ---- phase 2: cumprod scan + activation (waves 0..3, one per batch row) ----
  int wv = tid >> 6, lane = tid & 63;
  if (wv < 4) {
    int bi = wv;
    int b = bg * 4 + bi;
    const float* zxp = Zx + ((size_t)t_local*256 + b)*1024 + g*256;
    float carry = 1.0f;
    for (int s = 0; s < 4; s++) {
      int c2 = s*64 + lane;
      float z = zred[0][bi][c2] + zred[1][bi][c2] + zxp[c2];
      float v = __cosf(z);
#pragma unroll
      for (int off = 1; off < 64; off <<= 1) {
        float u = __shfl_up(v, (unsigned)off, 64);
        if (lane >= off) v *= u;
      }
      v *= carry;
      carry = __shfl(v, 63, 64);
      float outv = (g == 2) ? tanh_f(v) : sigm(v);
      gwr[((size_t)g*256 + b)*256 + c2] = outv;
    }
  }
}

// ---------------- host ----------------
extern "C" void kernel_launch(void* const* d_in, const int* in_sizes, int n_in,
                              void* d_out, int out_size, void* d_ws, size_t ws_size,
                              hipStream_t stream) {
  const float* x   = (const float*)d_in[0];
  const float* Wf  = (const float*)d_in[1];
  const float* bf_ = (const float*)d_in[2];
  const float* thf = (const float*)d_in[3];
  const float* Wi  = (const float*)d_in[4];
  const float* bi_ = (const float*)d_in[5];
  const float* thi = (const float*)d_in[6];
  const float* Wg  = (const float*)d_in[7];
  const float* bg_ = (const float*)d_in[8];
  const float* thg = (const float*)d_in[9];
  const float* Wo  = (const float*)d_in[10];
  const float* bo_ = (const float*)d_in[11];
  const float* tho = (const float*)d_in[12];
  float* out = (float*)d_out;

  char* ws = (char*)d_ws;
  size_t oWxC  = 0;                       // 1 MB
  size_t oWhT2 = oWxC  + 1048576;         // 512 KB
  size_t oCvec = oWhT2 + 524288;          // 4 KB
  size_t oCx0  = oCvec + 4096;            // 256 KB
  size_t oCx1  = oCx0  + 262144;          // 256 KB
  size_t oG0   = oCx1  + 262144;          // 1 MB
  size_t oG1   = oG0   + 1048576;         // 1 MB
  size_t oZx   = oG1   + 1048576;         // CT MB

  int CT = 1;
  const int cands[7] = {64, 32, 16, 8, 4, 2, 1};
  for (int i = 0; i < 7; i++) {
    if (oZx + (size_t)cands[i] * 1048576 <= ws_size) { CT = cands[i]; break; }
  }

  unsigned short* WxC  = (unsigned short*)(ws + oWxC);
  unsigned*       WhT2 = (unsigned*)(ws + oWhT2);
  float*          cvec = (float*)(ws + oCvec);
  float*          cx0  = (float*)(ws + oCx0);
  float*          cx1  = (float*)(ws + oCx1);
  float*          g0   = (float*)(ws + oG0);
  float*          g1   = (float*)(ws + oG1);
  float*          Zx   = (float*)(ws + oZx);

  prep_kernel<<<1024, 256, 0, stream>>>(Wf, Wi, Wg, Wo, bf_, bi_, bg_, bo_,
                                        thf, thi, thg, tho, WxC, WhT2, cvec);

  int nch = T_STEPS / CT;
  for (int c = 0; c < nch; c++) {
    const float* Xc = x + (size_t)c * CT * 256 * 512;
    xgemm_kernel<<<dim3(8, CT * 2), 256, 0, stream>>>(Xc, WxC, cvec, Zx);
    for (int tl = 0; tl < CT; tl++) {
      int t = c * CT + tl;
      step_kernel<<<256, 512, 0, stream>>>(t, tl, Zx, WhT2, g0, g1, cx0, cx1, out);
    }
  }
  // final update for t = T-1 (+ tails)
  step_kernel<<<256, 512, 0, stream>>>(T_STEPS, 0, Zx, WhT2, g0, g1, cx0, cx1, out);
}